// Round 1
// baseline (585.283 us; speedup 1.0000x reference)
//
#include <hip/hip_runtime.h>
#include <math.h>

#define B_    2048
#define N_    36
#define EMB_  1024
#define SIMD_ 16
#define HID_  32
#define K_    8

// One block per batch item b. 256 threads = 4 waves.
// Phase 0: prep folded weights in LDS (Wsum = sum_k gcn_w[k], weight-normed W1/w2).
// Phase 1: each wave computes block-wise cosine sims for 9 of the 36 rows
//          (fully coalesced float4 loads, 16-lane shfl_xor reductions).
// Phase 2: NOW CELL-PARALLEL across all 256 threads (was wave-0-only serial):
//          2A: g1[i][h] = sum_d sim[i][d]*Wsum[d][h]   (36x32 cells, 16 FMA each)
//          2B: t[i][h2] = tanh(b1[h2] + W1[h2,:].g1[i,:]) (36x32 cells, 32 FMA + tanh)
//          2C: s[i] = b2 + W2.t[i,:]; mean over i (wave 0, 36 lanes, butterfly)
//          This also removes the per-lane hid[32] array -> lower VGPR peak ->
//          better occupancy for the streaming phase 1.
// NOTE: the Gaussian-kernel graph weights row-normalize to sum S/(S+1e-8) ~= 1
// (error <= ~1.2e-8, far below the 1.55e-3 absmax threshold), and the node
// features are j-independent, so the whole pairwise-distance pipeline folds
// to identity. gk_mean/gk_prec are provably irrelevant at this tolerance.
__global__ __launch_bounds__(256) void simgsmn_kernel(
    const float* __restrict__ inp1, const float* __restrict__ inp2,
    const float* __restrict__ gcn_w,
    const float* __restrict__ out1_v, const float* __restrict__ out1_g,
    const float* __restrict__ out1_b,
    const float* __restrict__ out2_v, const float* __restrict__ out2_g,
    const float* __restrict__ out2_b,
    float* __restrict__ out)
{
    __shared__ float sSim[N_][SIMD_ + 1];   // +1 pad: kills stride-16 bank conflicts
    __shared__ float sWsum[SIMD_][HID_];    // read with lane along h (stride-1): conflict-free
    __shared__ float sW1[HID_][HID_ + 1];   // +1 pad: phase 2B reads h2 varying per lane
    __shared__ float sB1[HID_];
    __shared__ float sW2[HID_];
    __shared__ float sG[N_][HID_ + 1];      // g1 = sim . Wsum
    __shared__ float sT[N_][HID_ + 1];      // t  = tanh(b1 + W1 . g1)

    const int tid = threadIdx.x;
    const int b   = blockIdx.x;

    // ---- Phase 0: fold weights (reads hit L2 after first blocks) ----
    for (int idx = tid; idx < SIMD_ * HID_; idx += 256) {
        float s = 0.f;
        #pragma unroll
        for (int k = 0; k < K_; ++k) s += gcn_w[k * SIMD_ * HID_ + idx];
        sWsum[idx / HID_][idx % HID_] = s;
    }
    if (tid < HID_) {
        // weight-normed out1: W1[row] = g[row] * v[row] / (||v[row]|| + 1e-12)
        float nrm = 0.f;
        #pragma unroll
        for (int h = 0; h < HID_; ++h) { float v = out1_v[tid * HID_ + h]; nrm += v * v; }
        float sc = out1_g[tid] / (sqrtf(nrm) + 1e-12f);
        #pragma unroll
        for (int h = 0; h < HID_; ++h) sW1[tid][h] = out1_v[tid * HID_ + h] * sc;
        sB1[tid] = out1_b[tid];
    } else if (tid >= 64 && tid < 64 + HID_) {
        int h = tid - 64;
        float nrm = 0.f;
        #pragma unroll
        for (int j = 0; j < HID_; ++j) { float v = out2_v[j]; nrm += v * v; }
        sW2[h] = out2_g[0] * out2_v[h] / (sqrtf(nrm) + 1e-12f);
    }
    __syncthreads();

    // ---- Phase 1: block-wise cosine sims ----
    const int wave = tid >> 6;
    const int lane = tid & 63;
    const int g    = lane >> 4;     // 16-lane group id: 0..3

    for (int i = wave; i < N_; i += 4) {             // 9 rows per wave, uniform trip count
        const float4* p1 = reinterpret_cast<const float4*>(inp1 + ((size_t)b * N_ + i) * EMB_) + lane;
        const float4* p2 = reinterpret_cast<const float4*>(inp2 + ((size_t)b * N_ + i) * EMB_) + lane;
        float qq[4], cc[4], qc[4];
        #pragma unroll
        for (int u = 0; u < 4; ++u) {
            float4 q = p1[u * 64];                   // coalesced: 16B/lane contiguous
            float4 c = p2[u * 64];
            qq[u] = q.x * q.x + q.y * q.y + q.z * q.z + q.w * q.w;
            cc[u] = c.x * c.x + c.y * c.y + c.z * c.z + c.w * c.w;
            qc[u] = q.x * c.x + q.y * c.y + q.z * c.z + q.w * c.w;
        }
        // chunk u, lane group g covers sim block s = 4u + g; reduce over the 16 lanes
        #pragma unroll
        for (int u = 0; u < 4; ++u) {
            #pragma unroll
            for (int m = 1; m < 16; m <<= 1) {
                qq[u] += __shfl_xor(qq[u], m, 64);
                cc[u] += __shfl_xor(cc[u], m, 64);
                qc[u] += __shfl_xor(qc[u], m, 64);
            }
        }
        if ((lane & 15) == 0) {
            #pragma unroll
            for (int u = 0; u < 4; ++u) {
                float sim = qc[u] / ((sqrtf(qq[u]) + 1e-8f) * (sqrtf(cc[u]) + 1e-8f));
                sSim[i][4 * u + g] = sim;
            }
        }
    }
    __syncthreads();

    // ---- Phase 2A: g1[i][h] = sum_d sim[i][d] * Wsum[d][h] ----
    // 1152 cells over 256 threads (4-5 each). sSim reads broadcast (i,d uniform
    // per half-wave); sWsum reads stride-1 in h=lane: conflict-free.
    for (int c = tid; c < N_ * HID_; c += 256) {
        const int i = c >> 5;            // HID_ == 32
        const int h = c & (HID_ - 1);
        float a = 0.f;
        #pragma unroll
        for (int d = 0; d < SIMD_; ++d) a += sSim[i][d] * sWsum[d][h];
        sG[i][h] = a;
    }
    __syncthreads();

    // ---- Phase 2B: t[i][h2] = tanh(b1[h2] + sum_h W1[h2][h] * g1[i][h]) ----
    // sW1 padded to 33: addr = h2*33+h -> bank (h2+h)%32, distinct per lane.
    for (int c = tid; c < N_ * HID_; c += 256) {
        const int i  = c >> 5;
        const int h2 = c & (HID_ - 1);
        float a = sB1[h2];
        #pragma unroll
        for (int h = 0; h < HID_; ++h) a += sW1[h2][h] * sG[i][h];
        sT[i][h2] = tanhf(a);
    }
    __syncthreads();

    // ---- Phase 2C: row scores + mean (wave 0 only; tiny) ----
    if (tid < 64) {
        float sv = 0.f;
        if (tid < N_) {
            float acc = out2_b[0];
            #pragma unroll
            for (int h = 0; h < HID_; ++h) acc += sW2[h] * sT[tid][h];  // stride-33: conflict-free
            sv = acc;
        }
        #pragma unroll
        for (int m = 1; m < 64; m <<= 1) sv += __shfl_xor(sv, m, 64);
        if (tid == 0) out[b] = sv * (1.f / (float)N_);
    }
}

extern "C" void kernel_launch(void* const* d_in, const int* in_sizes, int n_in,
                              void* d_out, int out_size, void* d_ws, size_t ws_size,
                              hipStream_t stream) {
    const float* inp1   = (const float*)d_in[0];
    const float* inp2   = (const float*)d_in[1];
    // d_in[2] = gk_mean, d_in[3] = gk_prec: provably irrelevant (see kernel note)
    const float* gcn_w  = (const float*)d_in[4];
    const float* out1_v = (const float*)d_in[5];
    const float* out1_g = (const float*)d_in[6];
    const float* out1_b = (const float*)d_in[7];
    const float* out2_v = (const float*)d_in[8];
    const float* out2_g = (const float*)d_in[9];
    const float* out2_b = (const float*)d_in[10];
    float* out = (float*)d_out;

    simgsmn_kernel<<<B_, 256, 0, stream>>>(inp1, inp2, gcn_w,
                                           out1_v, out1_g, out1_b,
                                           out2_v, out2_g, out2_b, out);
}

// Round 5
// 578.836 us; speedup vs baseline: 1.0111x; 1.0111x over previous
//
#include <hip/hip_runtime.h>
#include <math.h>

#define B_    2048
#define N_    36
#define EMB_  1024
#define SIMD_ 16
#define HID_  32
#define K_    8

// One block per batch item b. 256 threads = 4 waves.
// Phase 0: fold weights in LDS (Wsum = sum_k gcn_w[k], weight-normed W1/w2).
// Phase 1: block-wise cosine sims. Lane mapping: lane l owns sim block s=l>>2
//          entirely (quarter c=l&3 reads float4s 16s+c+4u, u=0..3), so qq/cc/qc
//          accumulate IN-LANE across u and the cross-lane reduce is only 2
//          shfl_xor stages over 4 lanes (6 shuffles/row vs 48 before).
//          Explicit 2-deep pipeline: row i+4's 8 loads issue before row i's
//          reduce -> memory pipe stays fed through the (short) reduce chain.
// Phase 2: cell-parallel MLP across all 256 threads (2A/2B/2C).
// NOTE: the Gaussian-kernel graph weights row-normalize to sum S/(S+1e-8) ~= 1
// (error <= ~1.2e-8, far below the 1.55e-3 absmax threshold), and the node
// features are j-independent, so the whole pairwise-distance pipeline folds
// to identity. gk_mean/gk_prec are provably irrelevant at this tolerance.
__global__ __launch_bounds__(256) void simgsmn_kernel(
    const float* __restrict__ inp1, const float* __restrict__ inp2,
    const float* __restrict__ gcn_w,
    const float* __restrict__ out1_v, const float* __restrict__ out1_g,
    const float* __restrict__ out1_b,
    const float* __restrict__ out2_v, const float* __restrict__ out2_g,
    const float* __restrict__ out2_b,
    float* __restrict__ out)
{
    __shared__ float sSim[N_][SIMD_ + 1];   // +1 pad: kills stride-16 bank conflicts
    __shared__ float sWsum[SIMD_][HID_];    // read with lane along h (stride-1): conflict-free
    __shared__ float sW1[HID_][HID_ + 1];   // +1 pad: phase 2B reads h2 varying per lane
    __shared__ float sB1[HID_];
    __shared__ float sW2[HID_];
    __shared__ float sG[N_][HID_ + 1];      // g1 = sim . Wsum
    __shared__ float sT[N_][HID_ + 1];      // t  = tanh(b1 + W1 . g1)

    const int tid = threadIdx.x;
    const int b   = blockIdx.x;

    // ---- Phase 0: fold weights (reads hit L2 after first blocks) ----
    for (int idx = tid; idx < SIMD_ * HID_; idx += 256) {
        float s = 0.f;
        #pragma unroll
        for (int k = 0; k < K_; ++k) s += gcn_w[k * SIMD_ * HID_ + idx];
        sWsum[idx / HID_][idx % HID_] = s;
    }
    if (tid < HID_) {
        // weight-normed out1: W1[row] = g[row] * v[row] / (||v[row]|| + 1e-12)
        float nrm = 0.f;
        #pragma unroll
        for (int h = 0; h < HID_; ++h) { float v = out1_v[tid * HID_ + h]; nrm += v * v; }
        float sc = out1_g[tid] / (sqrtf(nrm) + 1e-12f);
        #pragma unroll
        for (int h = 0; h < HID_; ++h) sW1[tid][h] = out1_v[tid * HID_ + h] * sc;
        sB1[tid] = out1_b[tid];
    } else if (tid >= 64 && tid < 64 + HID_) {
        int h = tid - 64;
        float nrm = 0.f;
        #pragma unroll
        for (int j = 0; j < HID_; ++j) { float v = out2_v[j]; nrm += v * v; }
        sW2[h] = out2_g[0] * out2_v[h] / (sqrtf(nrm) + 1e-12f);
    }
    __syncthreads();

    // ---- Phase 1: block-wise cosine sims (pipelined, in-lane accumulation) ----
    const int wave = tid >> 6;
    const int lane = tid & 63;
    const int s    = lane >> 2;              // sim block 0..15 owned by this lane
    const int c4   = lane & 3;               // quarter of the 64-float block
    const int loff = 16 * s + c4;            // float4 offset within a row

    const float4* basep1 = reinterpret_cast<const float4*>(inp1 + (size_t)b * N_ * EMB_) + loff;
    const float4* basep2 = reinterpret_cast<const float4*>(inp2 + (size_t)b * N_ * EMB_) + loff;
    // row stride in float4 units = EMB_/4 = 256

    float4 qa[4], ca[4], qb[4], cb[4];
    {   // prologue: load row `wave`
        const float4* p1 = basep1 + wave * 256;
        const float4* p2 = basep2 + wave * 256;
        #pragma unroll
        for (int u = 0; u < 4; ++u) { qa[u] = p1[4 * u]; ca[u] = p2[4 * u]; }
    }
    #pragma unroll
    for (int it = 0; it < 9; ++it) {
        const int i = wave + 4 * it;
        if (it < 8) {                        // prefetch row i+4 (static unroll -> regs)
            const float4* p1 = basep1 + (i + 4) * 256;
            const float4* p2 = basep2 + (i + 4) * 256;
            #pragma unroll
            for (int u = 0; u < 4; ++u) { qb[u] = p1[4 * u]; cb[u] = p2[4 * u]; }
        }
        float qq = 0.f, cc = 0.f, qc = 0.f;
        #pragma unroll
        for (int u = 0; u < 4; ++u) {
            float4 q = qa[u], c = ca[u];
            qq += q.x * q.x + q.y * q.y + q.z * q.z + q.w * q.w;
            cc += c.x * c.x + c.y * c.y + c.z * c.z + c.w * c.w;
            qc += q.x * c.x + q.y * c.y + q.z * c.z + q.w * c.w;
        }
        // reduce over the 4 lanes sharing block s (2 butterfly stages)
        qq += __shfl_xor(qq, 1, 64);  cc += __shfl_xor(cc, 1, 64);  qc += __shfl_xor(qc, 1, 64);
        qq += __shfl_xor(qq, 2, 64);  cc += __shfl_xor(cc, 2, 64);  qc += __shfl_xor(qc, 2, 64);
        if (c4 == 0) {
            // eps terms are ~1e-9 relative (qq,cc ~ 64): rsqrt form is exact enough
            sSim[i][s] = qc * rsqrtf(qq * cc);
        }
        #pragma unroll
        for (int u = 0; u < 4; ++u) { qa[u] = qb[u]; ca[u] = cb[u]; }   // renamed by unroll
    }
    __syncthreads();

    // ---- Phase 2A: g1[i][h] = sum_d sim[i][d] * Wsum[d][h] ----
    for (int c = tid; c < N_ * HID_; c += 256) {
        const int i = c >> 5;            // HID_ == 32
        const int h = c & (HID_ - 1);
        float a = 0.f;
        #pragma unroll
        for (int d = 0; d < SIMD_; ++d) a += sSim[i][d] * sWsum[d][h];
        sG[i][h] = a;
    }
    __syncthreads();

    // ---- Phase 2B: t[i][h2] = tanh(b1[h2] + sum_h W1[h2][h] * g1[i][h]) ----
    for (int c = tid; c < N_ * HID_; c += 256) {
        const int i  = c >> 5;
        const int h2 = c & (HID_ - 1);
        float a = sB1[h2];
        #pragma unroll
        for (int h = 0; h < HID_; ++h) a += sW1[h2][h] * sG[i][h];
        sT[i][h2] = tanhf(a);
    }
    __syncthreads();

    // ---- Phase 2C: row scores + mean (wave 0 only; tiny) ----
    if (tid < 64) {
        float sv = 0.f;
        if (tid < N_) {
            float acc = out2_b[0];
            #pragma unroll
            for (int h = 0; h < HID_; ++h) acc += sW2[h] * sT[tid][h];  // stride-33: conflict-free
            sv = acc;
        }
        #pragma unroll
        for (int m = 1; m < 64; m <<= 1) sv += __shfl_xor(sv, m, 64);
        if (tid == 0) out[b] = sv * (1.f / (float)N_);
    }
}

extern "C" void kernel_launch(void* const* d_in, const int* in_sizes, int n_in,
                              void* d_out, int out_size, void* d_ws, size_t ws_size,
                              hipStream_t stream) {
    const float* inp1   = (const float*)d_in[0];
    const float* inp2   = (const float*)d_in[1];
    // d_in[2] = gk_mean, d_in[3] = gk_prec: provably irrelevant (see kernel note)
    const float* gcn_w  = (const float*)d_in[4];
    const float* out1_v = (const float*)d_in[5];
    const float* out1_g = (const float*)d_in[6];
    const float* out1_b = (const float*)d_in[7];
    const float* out2_v = (const float*)d_in[8];
    const float* out2_g = (const float*)d_in[9];
    const float* out2_b = (const float*)d_in[10];
    float* out = (float*)d_out;

    simgsmn_kernel<<<B_, 256, 0, stream>>>(inp1, inp2, gcn_w,
                                           out1_v, out1_g, out1_b,
                                           out2_v, out2_g, out2_b, out);
}

// Round 6
// 577.232 us; speedup vs baseline: 1.0139x; 1.0028x over previous
//
#include <hip/hip_runtime.h>
#include <math.h>

#define B_    2048
#define N_    36
#define EMB_  1024
#define SIMD_ 16
#define HID_  32
#define K_    8

// One block per batch item b. 256 threads = 4 waves.
// Phase 1 mapping (this round): CONTIGUOUS loads — instruction u has lane l
// reading float4 index 64u+l, i.e. one 1KB fully-coalesced transaction per
// instruction (best DRAM/L2 efficiency). Lane l's u-partial belongs to sim
// block 4u + (l>>4); the 16-lane reduction is done with DPP v_add stages
// (quad_perm xor1, quad_perm xor2, row_ror:4, row_ror:8) — pure VALU pipe,
// no ds_swizzle/lgkm round-trips. 2-deep prefetch pipeline kept from the
// measured round-1 kernel (row i+4 loads issue before row i's reduce).
// Phase 2: cell-parallel MLP across all 256 threads (2A/2B/2C).
// NOTE: the Gaussian-kernel graph weights row-normalize to sum S/(S+1e-8) ~= 1
// (error <= ~1.2e-8, far below the 1.55e-3 absmax threshold), and the node
// features are j-independent, so the whole pairwise-distance pipeline folds
// to identity. gk_mean/gk_prec are provably irrelevant at this tolerance.

// 16-lane (DPP-row) sum reduction stage: x += dpp(x, CTRL)
template<int CTRL>
__device__ __forceinline__ float dpp_add(float x) {
    int t = __builtin_amdgcn_update_dpp(0, __builtin_bit_cast(int, x),
                                        CTRL, 0xf, 0xf, false);
    return x + __builtin_bit_cast(float, t);
}
// full 16-lane sum: after these 4 stages every lane of the 16-lane DPP row
// holds the row sum (quad sums, then ror:4 + ror:8 sweep the 4 quads).
__device__ __forceinline__ float row16_sum(float x) {
    x = dpp_add<0xB1>(x);    // quad_perm [1,0,3,2]  (xor 1)
    x = dpp_add<0x4E>(x);    // quad_perm [2,3,0,1]  (xor 2)
    x = dpp_add<0x124>(x);   // row_ror:4
    x = dpp_add<0x128>(x);   // row_ror:8
    return x;
}

__global__ __launch_bounds__(256) void simgsmn_kernel(
    const float* __restrict__ inp1, const float* __restrict__ inp2,
    const float* __restrict__ gcn_w,
    const float* __restrict__ out1_v, const float* __restrict__ out1_g,
    const float* __restrict__ out1_b,
    const float* __restrict__ out2_v, const float* __restrict__ out2_g,
    const float* __restrict__ out2_b,
    float* __restrict__ out)
{
    __shared__ float sSim[N_][SIMD_ + 1];   // +1 pad: kills stride-16 bank conflicts
    __shared__ float sWsum[SIMD_][HID_];    // read with lane along h (stride-1): conflict-free
    __shared__ float sW1[HID_][HID_ + 1];   // +1 pad: phase 2B reads h2 varying per lane
    __shared__ float sB1[HID_];
    __shared__ float sW2[HID_];
    __shared__ float sG[N_][HID_ + 1];      // g1 = sim . Wsum
    __shared__ float sT[N_][HID_ + 1];      // t  = tanh(b1 + W1 . g1)

    const int tid = threadIdx.x;
    const int b   = blockIdx.x;

    // ---- Phase 0: fold weights (reads hit L2 after first blocks) ----
    for (int idx = tid; idx < SIMD_ * HID_; idx += 256) {
        float s = 0.f;
        #pragma unroll
        for (int k = 0; k < K_; ++k) s += gcn_w[k * SIMD_ * HID_ + idx];
        sWsum[idx / HID_][idx % HID_] = s;
    }
    if (tid < HID_) {
        // weight-normed out1: W1[row] = g[row] * v[row] / (||v[row]|| + 1e-12)
        float nrm = 0.f;
        #pragma unroll
        for (int h = 0; h < HID_; ++h) { float v = out1_v[tid * HID_ + h]; nrm += v * v; }
        float sc = out1_g[tid] / (sqrtf(nrm) + 1e-12f);
        #pragma unroll
        for (int h = 0; h < HID_; ++h) sW1[tid][h] = out1_v[tid * HID_ + h] * sc;
        sB1[tid] = out1_b[tid];
    } else if (tid >= 64 && tid < 64 + HID_) {
        int h = tid - 64;
        float nrm = 0.f;
        #pragma unroll
        for (int j = 0; j < HID_; ++j) { float v = out2_v[j]; nrm += v * v; }
        sW2[h] = out2_g[0] * out2_v[h] / (sqrtf(nrm) + 1e-12f);
    }
    __syncthreads();

    // ---- Phase 1: block-wise cosine sims (contiguous loads, DPP reduce) ----
    const int wave = tid >> 6;
    const int lane = tid & 63;
    const int g    = lane >> 4;              // 16-lane group id 0..3 (DPP row)

    const float4* basep1 = reinterpret_cast<const float4*>(inp1 + (size_t)b * N_ * EMB_) + lane;
    const float4* basep2 = reinterpret_cast<const float4*>(inp2 + (size_t)b * N_ * EMB_) + lane;
    // row stride in float4 units = EMB_/4 = 256; instr u reads float4 64u+lane

    float4 qa[4], ca[4], qb[4], cb[4];
    {   // prologue: load row `wave`
        const float4* p1 = basep1 + wave * 256;
        const float4* p2 = basep2 + wave * 256;
        #pragma unroll
        for (int u = 0; u < 4; ++u) { qa[u] = p1[64 * u]; ca[u] = p2[64 * u]; }
    }
    #pragma unroll
    for (int it = 0; it < 9; ++it) {
        const int i = wave + 4 * it;
        if (it < 8) {                        // prefetch row i+4 (static unroll -> regs)
            const float4* p1 = basep1 + (i + 4) * 256;
            const float4* p2 = basep2 + (i + 4) * 256;
            #pragma unroll
            for (int u = 0; u < 4; ++u) { qb[u] = p1[64 * u]; cb[u] = p2[64 * u]; }
        }
        #pragma unroll
        for (int u = 0; u < 4; ++u) {
            float4 q = qa[u], c = ca[u];
            float qq = q.x * q.x + q.y * q.y + q.z * q.z + q.w * q.w;
            float cc = c.x * c.x + c.y * c.y + c.z * c.z + c.w * c.w;
            float qc = q.x * c.x + q.y * c.y + q.z * c.z + q.w * c.w;
            // sum across the 16-lane DPP row: block s = 4u + g
            qq = row16_sum(qq);
            cc = row16_sum(cc);
            qc = row16_sum(qc);
            if ((lane & 15) == 0) {
                // eps terms are ~1e-9 relative (qq,cc ~ 64): rsqrt form is exact enough
                sSim[i][4 * u + g] = qc * rsqrtf(qq * cc);
            }
        }
        #pragma unroll
        for (int u = 0; u < 4; ++u) { qa[u] = qb[u]; ca[u] = cb[u]; }   // renamed by unroll
    }
    __syncthreads();

    // ---- Phase 2A: g1[i][h] = sum_d sim[i][d] * Wsum[d][h] ----
    for (int c = tid; c < N_ * HID_; c += 256) {
        const int i = c >> 5;            // HID_ == 32
        const int h = c & (HID_ - 1);
        float a = 0.f;
        #pragma unroll
        for (int d = 0; d < SIMD_; ++d) a += sSim[i][d] * sWsum[d][h];
        sG[i][h] = a;
    }
    __syncthreads();

    // ---- Phase 2B: t[i][h2] = tanh(b1[h2] + sum_h W1[h2][h] * g1[i][h]) ----
    for (int c = tid; c < N_ * HID_; c += 256) {
        const int i  = c >> 5;
        const int h2 = c & (HID_ - 1);
        float a = sB1[h2];
        #pragma unroll
        for (int h = 0; h < HID_; ++h) a += sW1[h2][h] * sG[i][h];
        sT[i][h2] = tanhf(a);
    }
    __syncthreads();

    // ---- Phase 2C: row scores + mean (wave 0 only; tiny) ----
    if (tid < 64) {
        float sv = 0.f;
        if (tid < N_) {
            float acc = out2_b[0];
            #pragma unroll
            for (int h = 0; h < HID_; ++h) acc += sW2[h] * sT[tid][h];  // stride-33: conflict-free
            sv = acc;
        }
        #pragma unroll
        for (int m = 1; m < 64; m <<= 1) sv += __shfl_xor(sv, m, 64);
        if (tid == 0) out[b] = sv * (1.f / (float)N_);
    }
}

extern "C" void kernel_launch(void* const* d_in, const int* in_sizes, int n_in,
                              void* d_out, int out_size, void* d_ws, size_t ws_size,
                              hipStream_t stream) {
    const float* inp1   = (const float*)d_in[0];
    const float* inp2   = (const float*)d_in[1];
    // d_in[2] = gk_mean, d_in[3] = gk_prec: provably irrelevant (see kernel note)
    const float* gcn_w  = (const float*)d_in[4];
    const float* out1_v = (const float*)d_in[5];
    const float* out1_g = (const float*)d_in[6];
    const float* out1_b = (const float*)d_in[7];
    const float* out2_v = (const float*)d_in[8];
    const float* out2_g = (const float*)d_in[9];
    const float* out2_b = (const float*)d_in[10];
    float* out = (float*)d_out;

    simgsmn_kernel<<<B_, 256, 0, stream>>>(inp1, inp2, gcn_w,
                                           out1_v, out1_g, out1_b,
                                           out2_v, out2_g, out2_b, out);
}